// Round 3
// baseline (3629.041 us; speedup 1.0000x reference)
//
#include <hip/hip_runtime.h>
#include <math.h>
#include <float.h>

#define N_ROWS 32768
#define EDIM 256
#define NE 8192
#define NQ 8                 // k-range splits across blocks
#define KRANGE (NE / NQ)     // 1024 k per block
#define KC 32                // k per LDS chunk

// ---- workspace layout (bytes) ----
#define OFF_ZNORM ((size_t)0)                 // 32768 f = 131072
#define OFF_ENORM (OFF_ZNORM + 131072)        // 8192 f  = 32768
#define OFF_PV    (OFF_ENORM + 32768)         // NQ*32768 f = 1048576
#define OFF_PI    (OFF_PV + 1048576)          // NQ*32768 i = 1048576
#define OFF_IDX   (OFF_PI + 1048576)          // 32768 i = 131072
#define OFF_BINS  (OFF_IDX + 131072)          // 8192 f = 32768
#define OFF_LOSS  (OFF_BINS + 32768)          // double

// numpy pairwise-sum emulation of sum(a*a) for n=256 contiguous fp32.
// numpy: n=256 -> recurse two 128-blocks; each 128-block = 8-accumulator
// unrolled loop, combined ((r0+r1)+(r2+r3))+((r4+r5)+(r6+r7)); halves added.
// contract(off): each product rounds fp32 before the add (no FMA fusion).
__device__ __forceinline__ float np_pairwise_sumsq(const float* __restrict__ a) {
#pragma clang fp contract(off)
    float h0, h1;
    #pragma unroll 1
    for (int hb = 0; hb < 2; ++hb) {
        const float* p = a + hb * 128;
        float r0=p[0]*p[0], r1=p[1]*p[1], r2=p[2]*p[2], r3=p[3]*p[3],
              r4=p[4]*p[4], r5=p[5]*p[5], r6=p[6]*p[6], r7=p[7]*p[7];
        #pragma unroll 1
        for (int i = 8; i < 128; i += 8) {
            r0 += p[i+0]*p[i+0]; r1 += p[i+1]*p[i+1];
            r2 += p[i+2]*p[i+2]; r3 += p[i+3]*p[i+3];
            r4 += p[i+4]*p[i+4]; r5 += p[i+5]*p[i+5];
            r6 += p[i+6]*p[i+6]; r7 += p[i+7]*p[i+7];
        }
        float s = ((r0+r1)+(r2+r3))+((r4+r5)+(r6+r7));
        if (hb == 0) h0 = s; else h1 = s;
    }
    return h0 + h1;
}

__global__ void k_znorm(const float* __restrict__ Z, float* __restrict__ zn) {
    int n = blockIdx.x * 256 + threadIdx.x;
    zn[n] = np_pairwise_sumsq(Z + (size_t)n * EDIM);
}
__global__ void k_enorm(const float* __restrict__ E, float* __restrict__ en) {
    int k = blockIdx.x * 256 + threadIdx.x;
    en[k] = np_pairwise_sumsq(E + (size_t)k * EDIM);
}

// Fused dot + argmin emulating the np reference bit-for-bit:
//   dot: single fp32 accumulator, sequential fmaf over d=0..255 ascending
//        (BLAS sgemm microkernel model)
//   score: S = fl32(zn + en); d = fl32(S - 2f*dot)   (contract off)
//   argmin: strict < over ascending k == np first-occurrence tie-break
__global__ __launch_bounds__(256, 2) void k_main(
    const float* __restrict__ Z, const float* __restrict__ E,
    const float* __restrict__ znorm, const float* __restrict__ enorm,
    float* __restrict__ pv, int* __restrict__ pi)
{
    __shared__ float4 etv4[KC * 64];   // 32 rows x 64 float4 = 32 KB
    int t  = threadIdx.x;
    int q  = blockIdx.x & (NQ - 1);
    int rg = blockIdx.x >> 3;
    int n0 = rg * 512 + t;
    int n1 = n0 + 256;
    int kb = q * KRANGE;

    const float4* Zv = (const float4*)Z;
    const float4* Ev = (const float4*)E;
    const float4* zp0 = Zv + (size_t)n0 * 64;
    const float4* zp1 = Zv + (size_t)n1 * 64;

    float zn0 = znorm[n0];
    float zn1 = znorm[n1];

    float b0 = FLT_MAX, b1 = FLT_MAX;
    int   i0 = 0,       i1 = 0;

    for (int c = 0; c < KRANGE / KC; ++c) {
        int kc = kb + c * KC;
        // stage E chunk: 2048 float4, 8 per thread; coalesced global, linear LDS
        #pragma unroll
        for (int j = 0; j < 8; ++j) {
            int f4i = j * 256 + t;
            etv4[f4i] = Ev[(size_t)(kc + (f4i >> 6)) * 64 + (f4i & 63)];
        }
        __syncthreads();

        float acc0[KC], acc1[KC];
        #pragma unroll
        for (int kk = 0; kk < KC; ++kk) { acc0[kk] = 0.f; acc1[kk] = 0.f; }

        for (int dc = 0; dc < 4; ++dc) {
            const float4* zpa = zp0 + dc * 16;
            const float4* zpb = zp1 + dc * 16;
            float4 za = zpa[0], zb = zpb[0];
            #pragma unroll 1
            for (int dd = 0; dd < 16; ++dd) {
                int nx = dd < 15 ? dd + 1 : 15;     // clamped preload (no OOB)
                float4 zaN = zpa[nx];
                float4 zbN = zpb[nx];
                const float4* ep = etv4 + dc * 16 + dd;
                #pragma unroll
                for (int kk = 0; kk < KC; ++kk) {
                    float4 e4 = ep[kk * 64];        // wave-uniform broadcast
                    acc0[kk] = fmaf(za.x, e4.x, acc0[kk]);
                    acc0[kk] = fmaf(za.y, e4.y, acc0[kk]);
                    acc0[kk] = fmaf(za.z, e4.z, acc0[kk]);
                    acc0[kk] = fmaf(za.w, e4.w, acc0[kk]);
                    acc1[kk] = fmaf(zb.x, e4.x, acc1[kk]);
                    acc1[kk] = fmaf(zb.y, e4.y, acc1[kk]);
                    acc1[kk] = fmaf(zb.z, e4.z, acc1[kk]);
                    acc1[kk] = fmaf(zb.w, e4.w, acc1[kk]);
                }
                za = zaN; zb = zbN;
            }
        }
        // np-emulated score; strict < with ascending k == first-min tie-break
        {
#pragma clang fp contract(off)
            #pragma unroll
            for (int kk = 0; kk < KC; ++kk) {
                int kg = kc + kk;
                float en = enorm[kg];
                float Sa = zn0 + en;
                float Sb = zn1 + en;
                float ta = 2.0f * acc0[kk];
                float tb = 2.0f * acc1[kk];
                float da = Sa - ta;
                float db = Sb - tb;
                if (da < b0) { b0 = da; i0 = kg; }
                if (db < b1) { b1 = db; i1 = kg; }
            }
        }
        __syncthreads();
    }
    size_t o0 = (size_t)q * N_ROWS + n0;
    size_t o1 = (size_t)q * N_ROWS + n1;
    pv[o0] = b0; pi[o0] = i0;
    pv[o1] = b1; pi[o1] = i1;
}

// merge NQ partials per row; ascending q == ascending k ranges, strict <
// keeps the lowest-k occurrence on exact fp32 ties (np argmin semantics)
__global__ void k_merge(const float* __restrict__ pv, const int* __restrict__ pi,
                        float* __restrict__ out_idx_f, int* __restrict__ idxint) {
    int g = blockIdx.x * 256 + threadIdx.x;
    float B = FLT_MAX; int I = 0;
    #pragma unroll
    for (int p = 0; p < NQ; ++p) {
        size_t o = (size_t)p * N_ROWS + g;
        float v = pv[o];
        if (v < B) { B = v; I = pi[o]; }
    }
    out_idx_f[g] = (float)I;
    idxint[g] = I;
}

// z_q_st = z + (e[idx]-z); loss partial = sum((e-z)^2)
__global__ void k_gather(const float* __restrict__ Z, const float* __restrict__ E,
                         const int* __restrict__ idxint,
                         float* __restrict__ out0, double* __restrict__ lossacc) {
    __shared__ float wsum[4];
    int t = threadIdx.x;
    size_t i = (size_t)blockIdx.x * 256 + t;
    int row  = (int)(i >> 6);
    int lane = t & 63;
    int f4   = (int)(i & 63);
    int idx = idxint[row];
    const float4* Zv = (const float4*)Z;
    const float4* Ev = (const float4*)E;
    float4 z4 = Zv[i];
    float4 e4 = Ev[(size_t)idx * 64 + f4];
    float4 d4; d4.x = e4.x - z4.x; d4.y = e4.y - z4.y; d4.z = e4.z - z4.z; d4.w = e4.w - z4.w;
    float4 o;  o.x = z4.x + d4.x;  o.y = z4.y + d4.y;  o.z = z4.z + d4.z;  o.w = z4.w + d4.w;
    ((float4*)out0)[i] = o;
    float q2 = d4.x*d4.x + d4.y*d4.y + d4.z*d4.z + d4.w*d4.w;
    #pragma unroll
    for (int off = 32; off > 0; off >>= 1) q2 += __shfl_down(q2, off, 64);
    if (lane == 0) wsum[t >> 6] = q2;
    __syncthreads();
    if (t == 0) {
        float s = wsum[0] + wsum[1] + wsum[2] + wsum[3];
        atomicAdd(lossacc, (double)s);
    }
}

// segment sums: bins += 1, dw += z  (one wave per row, coalesced dword atomics)
__global__ void k_scatter(const float* __restrict__ Z, const int* __restrict__ idxint,
                          float* __restrict__ dw, float* __restrict__ bins) {
    int t = threadIdx.x;
    int w = t >> 6, lane = t & 63;
    int row = blockIdx.x * 4 + w;
    int idx = idxint[row];
    const float4* Zv = (const float4*)Z;
    float4 z4 = Zv[(size_t)row * 64 + lane];
    float* dp = dw + (size_t)idx * 256 + lane * 4;
    atomicAdd(dp + 0, z4.x);
    atomicAdd(dp + 1, z4.y);
    atomicAdd(dp + 2, z4.z);
    atomicAdd(dp + 3, z4.w);
    if (lane == 0) atomicAdd(&bins[idx], 1.0f);
}

// new_emb = dw / cluster (in-place on out3), + loss
__global__ void k_final(const float* __restrict__ bins, const double* __restrict__ lossacc,
                        float* __restrict__ out3, float* __restrict__ out2) {
    size_t i = (size_t)blockIdx.x * 256 + threadIdx.x;  // 2097152 scalar elems
    int k = (int)(i >> 8);
    // n = sum(bins) = 32768 exactly (each row lands in exactly one bin)
    float cl = (bins[k] + 1e-5f) / (32768.0f + 8192.0f * 1e-5f) * 32768.0f;
    out3[i] = out3[i] / cl;
    if (blockIdx.x == 0 && threadIdx.x == 0) {
        out2[0] = 0.25f * (float)(lossacc[0] / 8388608.0);
    }
}

extern "C" void kernel_launch(void* const* d_in, const int* in_sizes, int n_in,
                              void* d_out, int out_size, void* d_ws, size_t ws_size,
                              hipStream_t stream) {
    const float* Z = (const float*)d_in[0];   // [32768, 256]
    const float* E = (const float*)d_in[1];   // [8192, 256]
    float* out  = (float*)d_out;
    float* out0 = out;                         // z_q_st  (8388608)
    float* out1 = out + 8388608;               // idx as float (32768)
    float* out2 = out1 + 32768;                // loss (1)
    float* out3 = out2 + 1;                    // new_embeddings (2097152)

    char* ws = (char*)d_ws;
    float* znorm   = (float*)(ws + OFF_ZNORM);
    float* enorm   = (float*)(ws + OFF_ENORM);
    float* pv      = (float*)(ws + OFF_PV);
    int*   pi      = (int*)  (ws + OFF_PI);
    int*   idxint  = (int*)  (ws + OFF_IDX);
    float* bins    = (float*)(ws + OFF_BINS);
    double* lossacc= (double*)(ws + OFF_LOSS);

    hipMemsetAsync(bins,    0, (size_t)NE * 4, stream);
    hipMemsetAsync(lossacc, 0, 8, stream);
    hipMemsetAsync(out3,    0, (size_t)NE * EDIM * 4, stream);

    k_znorm  <<<N_ROWS / 256,  256, 0, stream>>>(Z, znorm);
    k_enorm  <<<NE / 256,      256, 0, stream>>>(E, enorm);
    k_main   <<<(N_ROWS/512)*NQ, 256, 0, stream>>>(Z, E, znorm, enorm, pv, pi);
    k_merge  <<<N_ROWS / 256,  256, 0, stream>>>(pv, pi, out1, idxint);
    k_gather <<<8388608/1024,  256, 0, stream>>>(Z, E, idxint, out0, lossacc);
    k_scatter<<<N_ROWS / 4,    256, 0, stream>>>(Z, idxint, out3, bins);
    k_final  <<<(NE*EDIM)/256, 256, 0, stream>>>(bins, lossacc, out3, out2);
}

// Round 4
// 1431.025 us; speedup vs baseline: 2.5360x; 2.5360x over previous
//
#include <hip/hip_runtime.h>
#include <math.h>
#include <float.h>

#define N_ROWS 32768
#define EDIM 256
#define NE 8192
#define NTILES 64            // 8192 / 128 n-tiles -> partials per row
#define DELTA 4e-4f          // rescue margin: > 2*(eps_mfma + eps_np + eps_epilogue)

typedef unsigned int uint32;
typedef unsigned short ushort16;
typedef __attribute__((ext_vector_type(8))) short bf16x8;   // 8 bf16 = 4 VGPRs
typedef __attribute__((ext_vector_type(4))) float f32x4;

// ---- workspace layout (bytes) ----
#define OFF_ZCAT    ((size_t)0)           // 32768 x 512 bf16 (hi|lo) = 33554432
#define OFF_ECAT    ((size_t)33554432)    //  8192 x 512 bf16 (hi|lo) = 8388608
#define OFF_ET      ((size_t)41943040)    //  256 x 8192 f32 (E^T)    = 8388608
#define OFF_ZN      ((size_t)50331648)    // 32768 f
#define OFF_EN      ((size_t)50462720)    //  8192 f
#define OFF_PV      ((size_t)50495488)    // 64 x 32768 f
#define OFF_PI      ((size_t)58884096)    // 64 x 32768 i
#define OFF_PV2     ((size_t)67272704)    // 64 x 32768 f
#define OFF_IDX     ((size_t)75661312)    // 32768 i
#define OFF_BINS    ((size_t)75792384)    //  8192 f
#define OFF_FLAGCNT ((size_t)75825152)    // int (padded)
#define OFF_LOSS    ((size_t)75825408)    // double (padded)
#define OFF_FLAGGED ((size_t)75825664)    // 32768 i

__device__ __forceinline__ ushort16 f32_to_bf16_rne(float f) {
    uint32 u = __float_as_uint(f);
    uint32 r = u + 0x7fffu + ((u >> 16) & 1u);
    return (ushort16)(r >> 16);
}

__device__ __forceinline__ void gload_lds16(const void* g, void* l) {
    __builtin_amdgcn_global_load_lds(
        (const __attribute__((address_space(1))) uint32*)g,
        (__attribute__((address_space(3))) uint32*)l, 16, 0, 0);
}

// numpy pairwise-sum emulation of sum(a*a) for n=256 (validated round 3)
__device__ __forceinline__ float np_pairwise_sumsq(const float* __restrict__ a) {
#pragma clang fp contract(off)
    float h0, h1;
    #pragma unroll 1
    for (int hb = 0; hb < 2; ++hb) {
        const float* p = a + hb * 128;
        float r0=p[0]*p[0], r1=p[1]*p[1], r2=p[2]*p[2], r3=p[3]*p[3],
              r4=p[4]*p[4], r5=p[5]*p[5], r6=p[6]*p[6], r7=p[7]*p[7];
        #pragma unroll 1
        for (int i = 8; i < 128; i += 8) {
            r0 += p[i+0]*p[i+0]; r1 += p[i+1]*p[i+1];
            r2 += p[i+2]*p[i+2]; r3 += p[i+3]*p[i+3];
            r4 += p[i+4]*p[i+4]; r5 += p[i+5]*p[i+5];
            r6 += p[i+6]*p[i+6]; r7 += p[i+7]*p[i+7];
        }
        float s = ((r0+r1)+(r2+r3))+((r4+r5)+(r6+r7));
        if (hb == 0) h0 = s; else h1 = s;
    }
    return h0 + h1;
}

__global__ void k_znorm(const float* __restrict__ Z, float* __restrict__ zn) {
    int n = blockIdx.x * 256 + threadIdx.x;
    zn[n] = np_pairwise_sumsq(Z + (size_t)n * EDIM);
}
__global__ void k_enorm(const float* __restrict__ E, float* __restrict__ en) {
    int k = blockIdx.x * 256 + threadIdx.x;
    en[k] = np_pairwise_sumsq(E + (size_t)k * EDIM);
}

// split Z into bf16 hi|lo, layout [m][0:256]=hi, [m][256:512]=lo
__global__ void k_convert_z(const float* __restrict__ Z, ushort16* __restrict__ Zcat) {
    size_t i = (size_t)blockIdx.x * 256 + threadIdx.x;   // float4 index
    float4 z4 = ((const float4*)Z)[i];
    int m = (int)(i >> 6), d4 = (int)(i & 63);
    float zf[4] = {z4.x, z4.y, z4.z, z4.w};
    ushort16 h[4], l[4];
    #pragma unroll
    for (int c = 0; c < 4; ++c) {
        ushort16 hh = f32_to_bf16_rne(zf[c]);
        float hf = __uint_as_float((uint32)hh << 16);
        h[c] = hh;
        l[c] = f32_to_bf16_rne(zf[c] - hf);
    }
    *(ushort4*)(Zcat + (size_t)m*512 + d4*4)       = make_ushort4(h[0],h[1],h[2],h[3]);
    *(ushort4*)(Zcat + (size_t)m*512 + 256 + d4*4) = make_ushort4(l[0],l[1],l[2],l[3]);
}

// split E into bf16 hi|lo + build f32 E^T [256][8192] for phase-B coalescing
__global__ void k_convert_e(const float* __restrict__ E, ushort16* __restrict__ Ecat,
                            float* __restrict__ ET) {
    size_t i = (size_t)blockIdx.x * 256 + threadIdx.x;
    float4 e4 = ((const float4*)E)[i];
    int k = (int)(i >> 6), d4 = (int)(i & 63);
    float ef[4] = {e4.x, e4.y, e4.z, e4.w};
    ushort16 h[4], l[4];
    #pragma unroll
    for (int c = 0; c < 4; ++c) {
        ushort16 hh = f32_to_bf16_rne(ef[c]);
        float hf = __uint_as_float((uint32)hh << 16);
        h[c] = hh;
        l[c] = f32_to_bf16_rne(ef[c] - hf);
        ET[(size_t)(d4*4 + c)*NE + k] = ef[c];
    }
    *(ushort4*)(Ecat + (size_t)k*512 + d4*4)       = make_ushort4(h[0],h[1],h[2],h[3]);
    *(ushort4*)(Ecat + (size_t)k*512 + 256 + d4*4) = make_ushort4(l[0],l[1],l[2],l[3]);
}

// merge two top-2 sets across 16-lane groups (butterfly), lex tie-break on idx
__device__ __forceinline__ void top2_shfl16(float& v1, int& i1, float& v2) {
    #pragma unroll
    for (int off = 1; off < 16; off <<= 1) {
        float ov1 = __shfl_xor(v1, off, 64);
        int   oi1 = __shfl_xor(i1, off, 64);
        float ov2 = __shfl_xor(v2, off, 64);
        bool take = (ov1 < v1) || (ov1 == v1 && oi1 < i1);
        float w1 = take ? ov1 : v1;
        int   wi = take ? oi1 : i1;
        float l1 = take ? v1  : ov1;
        v2 = fminf(fminf(v2, ov2), l1);
        v1 = w1; i1 = wi;
    }
}

// Phase A: bf16-split MFMA GEMM (virtual K=768: hi.hi + hi.lo + lo.hi) with
// fused per-row top-2 argmin epilogue. m97 structure: 128x128 tile, BK=32,
// global_load_lds width=16 staging, 16x16x32 bf16 MFMA.
__global__ __launch_bounds__(256, 2) void k_gemm(
    const ushort16* __restrict__ Zcat, const ushort16* __restrict__ Ecat,
    const float* __restrict__ znorm, const float* __restrict__ enorm,
    float* __restrict__ pv, int* __restrict__ pi, float* __restrict__ pv2)
{
    __shared__ ushort16 As[128*32];   // [row][k] 64 B rows, 8 KB
    __shared__ ushort16 Bs[128*32];
    __shared__ float zns[128], ens[128];
    __shared__ float cv1[2][128]; __shared__ int ci1[2][128]; __shared__ float cv2[2][128];

    int t = threadIdx.x;
    int nt = blockIdx.x & 63, mt = blockIdx.x >> 6;   // n fastest: A-band L2 reuse
    int wid = t >> 6, lane = t & 63;
    int wm = (wid >> 1) * 64, wn = (wid & 1) * 64;

    if (t < 128) { zns[t] = znorm[mt*128 + t]; ens[t] = enorm[nt*128 + t]; }

    // staging: wave wid stores LDS j-blocks {2w, 2w+1} for A and B.
    // j-block = 16 rows x 64 B; lane r -> row j*16 + r/4, 16-B quarter r%4.
    int j0 = wid*2, j1 = j0 + 1;
    int r0 = j0*16 + (lane >> 2), r1 = j1*16 + (lane >> 2);
    int c8 = (lane & 3) * 8;
    const ushort16* gA = Zcat + (size_t)mt*128*512;
    const ushort16* gB = Ecat + (size_t)nt*128*512;
    const ushort16* gA0 = gA + (size_t)r0*512 + c8;
    const ushort16* gA1 = gA + (size_t)r1*512 + c8;
    const ushort16* gB0 = gB + (size_t)r0*512 + c8;
    const ushort16* gB1 = gB + (size_t)r1*512 + c8;
    ushort16* lA0 = As + j0*512;  ushort16* lA1 = As + j1*512;
    ushort16* lB0 = Bs + j0*512;  ushort16* lB1 = Bs + j1*512;

    f32x4 acc[4][4];
    #pragma unroll
    for (int i = 0; i < 4; ++i)
        #pragma unroll
        for (int j = 0; j < 4; ++j) acc[i][j] = (f32x4){0.f,0.f,0.f,0.f};

    // fragment addresses: row = lane&15 (+16*i), k-offset = (lane>>4)*8
    int frow = lane & 15, fko = (lane >> 4) * 8;
    const ushort16* aBase = As + (wm + frow)*32 + fko;
    const ushort16* bBase = Bs + (wn + frow)*32 + fko;

    // 24 chunks of 32: seg0 = Ah.Eh, seg1 = Ah.El, seg2 = Al.Eh
    #pragma unroll 1
    for (int c = 0; c < 24; ++c) {
        int seg = c >> 3, w8 = c & 7;
        int aOff = w8*32 + (seg == 2 ? 256 : 0);
        int bOff = w8*32 + (seg == 1 ? 256 : 0);
        gload_lds16(gA0 + aOff, lA0);
        gload_lds16(gA1 + aOff, lA1);
        gload_lds16(gB0 + bOff, lB0);
        gload_lds16(gB1 + bOff, lB1);
        __syncthreads();
        bf16x8 af[4], bfr[4];
        #pragma unroll
        for (int i = 0; i < 4; ++i) {
            af[i]  = *(const bf16x8*)(aBase + i*16*32);
            bfr[i] = *(const bf16x8*)(bBase + i*16*32);
        }
        #pragma unroll
        for (int i = 0; i < 4; ++i)
            #pragma unroll
            for (int j = 0; j < 4; ++j)
                acc[i][j] = __builtin_amdgcn_mfma_f32_16x16x32_bf16(af[i], bfr[j], acc[i][j], 0, 0, 0);
        __syncthreads();
    }

    // epilogue: D layout n = lane&15, m = (lane>>4)*4 + reg
    int q = lane >> 4;
    #pragma unroll
    for (int i = 0; i < 4; ++i) {
        #pragma unroll
        for (int r = 0; r < 4; ++r) {
            int mloc = wm + i*16 + q*4 + r;
            float zn = zns[mloc];
            float s[4]; int nn[4];
            #pragma unroll
            for (int j = 0; j < 4; ++j) {
                int nl = wn + j*16 + frow;
                nn[j] = nt*128 + nl;
                s[j] = (zn + ens[nl]) - 2.0f * acc[i][j][r];
            }
            float v1 = s[0], v2 = FLT_MAX; int i1 = nn[0];
            #pragma unroll
            for (int j = 1; j < 4; ++j) {
                if (s[j] < v1) { v2 = v1; v1 = s[j]; i1 = nn[j]; }
                else v2 = fminf(v2, s[j]);
            }
            top2_shfl16(v1, i1, v2);
            if (frow == 0) { cv1[wid&1][mloc] = v1; ci1[wid&1][mloc] = i1; cv2[wid&1][mloc] = v2; }
        }
    }
    __syncthreads();
    if (t < 128) {
        float v1 = cv1[0][t], v2 = cv2[0][t]; int i1 = ci1[0][t];
        float o1 = cv1[1][t], o2 = cv2[1][t]; int oi = ci1[1][t];
        if (o1 < v1 || (o1 == v1 && oi < i1)) { v2 = fminf(v1, o2); v1 = o1; i1 = oi; }
        else v2 = fminf(v2, o1);
        size_t o = (size_t)nt * N_ROWS + mt*128 + t;
        pv[o] = v1; pi[o] = i1; pv2[o] = v2;
    }
}

// merge 64 n-tile partials per row; flag rows with gap < DELTA for np-exact rescan
__global__ void k_merge(const float* __restrict__ pv, const int* __restrict__ pi,
                        const float* __restrict__ pv2,
                        float* __restrict__ out_idx_f, int* __restrict__ idxint,
                        int* __restrict__ flagcnt, int* __restrict__ flagged) {
    int g = blockIdx.x * 256 + threadIdx.x;
    float B1 = FLT_MAX, B2 = FLT_MAX; int I1 = 0;
    #pragma unroll 1
    for (int p = 0; p < NTILES; ++p) {   // ascending p == ascending k
        size_t o = (size_t)p * N_ROWS + g;
        float v1 = pv[o], v2 = pv2[o]; int i1 = pi[o];
        if (v1 < B1) { B2 = fminf(B1, v2); B1 = v1; I1 = i1; }
        else B2 = fminf(B2, v1);
    }
    out_idx_f[g] = (float)I1;
    idxint[g] = I1;
    if (B2 - B1 < DELTA) {
        int slot = atomicAdd(flagcnt, 1);
        flagged[slot] = g;
    }
}

// Phase B: full np-exact fp32 rescan (validated round-3 semantics) for flagged rows
__global__ void k_phaseB(const float* __restrict__ Z, const float* __restrict__ ET,
                         const float* __restrict__ znorm, const float* __restrict__ enorm,
                         const int* __restrict__ flagcnt, const int* __restrict__ flagged,
                         float* __restrict__ out_idx_f, int* __restrict__ idxint) {
    __shared__ float zl[256];
    __shared__ float sv[256]; __shared__ int si[256];
    int t = threadIdx.x;
    int cnt = *flagcnt; if (cnt > N_ROWS) cnt = N_ROWS;
    for (int f = blockIdx.x; f < cnt; f += gridDim.x) {
        int row = flagged[f];
        __syncthreads();
        zl[t] = Z[(size_t)row*EDIM + t];
        __syncthreads();
        float zn = znorm[row];
        float bv = FLT_MAX; int bi = 0x7fffffff;
        #pragma unroll 1
        for (int j = 0; j < 32; j += 4) {
            float d0=0.f, d1=0.f, d2=0.f, d3=0.f;
            const float* eb = ET + t + j*256;
            #pragma unroll 1
            for (int d = 0; d < 256; ++d) {       // sequential ascending d per chain
                float zd = zl[d];
                const float* ep = eb + (size_t)d*NE;
                d0 = fmaf(zd, ep[0],   d0);
                d1 = fmaf(zd, ep[256], d1);
                d2 = fmaf(zd, ep[512], d2);
                d3 = fmaf(zd, ep[768], d3);
            }
            {
#pragma clang fp contract(off)
                float dd[4] = {d0, d1, d2, d3};
                #pragma unroll
                for (int c = 0; c < 4; ++c) {
                    int k = t + (j + c)*256;
                    float S  = zn + enorm[k];
                    float tw = 2.0f * dd[c];
                    float sc = S - tw;
                    if (sc < bv || (sc == bv && k < bi)) { bv = sc; bi = k; }
                }
            }
        }
        sv[t] = bv; si[t] = bi;
        __syncthreads();
        for (int st = 128; st > 0; st >>= 1) {
            if (t < st) {
                float ov = sv[t+st]; int oi = si[t+st];
                if (ov < sv[t] || (ov == sv[t] && oi < si[t])) { sv[t] = ov; si[t] = oi; }
            }
            __syncthreads();
        }
        if (t == 0) { out_idx_f[row] = (float)si[0]; idxint[row] = si[0]; }
    }
}

// z_q_st = z + (e[idx]-z); loss partial = sum((e-z)^2)
__global__ void k_gather(const float* __restrict__ Z, const float* __restrict__ E,
                         const int* __restrict__ idxint,
                         float* __restrict__ out0, double* __restrict__ lossacc) {
    __shared__ float wsum[4];
    int t = threadIdx.x;
    size_t i = (size_t)blockIdx.x * 256 + t;
    int row  = (int)(i >> 6);
    int lane = t & 63;
    int f4   = (int)(i & 63);
    int idx = idxint[row];
    float4 z4 = ((const float4*)Z)[i];
    float4 e4 = ((const float4*)E)[(size_t)idx * 64 + f4];
    float4 d4; d4.x = e4.x - z4.x; d4.y = e4.y - z4.y; d4.z = e4.z - z4.z; d4.w = e4.w - z4.w;
    float4 o;  o.x = z4.x + d4.x;  o.y = z4.y + d4.y;  o.z = z4.z + d4.z;  o.w = z4.w + d4.w;
    ((float4*)out0)[i] = o;
    float q2 = d4.x*d4.x + d4.y*d4.y + d4.z*d4.z + d4.w*d4.w;
    #pragma unroll
    for (int off = 32; off > 0; off >>= 1) q2 += __shfl_down(q2, off, 64);
    if (lane == 0) wsum[t >> 6] = q2;
    __syncthreads();
    if (t == 0) atomicAdd(lossacc, (double)(wsum[0] + wsum[1] + wsum[2] + wsum[3]));
}

// segment sums: bins += 1, dw += z
__global__ void k_scatter(const float* __restrict__ Z, const int* __restrict__ idxint,
                          float* __restrict__ dw, float* __restrict__ bins) {
    int t = threadIdx.x;
    int w = t >> 6, lane = t & 63;
    int row = blockIdx.x * 4 + w;
    int idx = idxint[row];
    float4 z4 = ((const float4*)Z)[(size_t)row * 64 + lane];
    float* dp = dw + (size_t)idx * 256 + lane * 4;
    atomicAdd(dp + 0, z4.x);
    atomicAdd(dp + 1, z4.y);
    atomicAdd(dp + 2, z4.z);
    atomicAdd(dp + 3, z4.w);
    if (lane == 0) atomicAdd(&bins[idx], 1.0f);
}

// new_emb = dw / cluster (in-place on out3), + loss
__global__ void k_final(const float* __restrict__ bins, const double* __restrict__ lossacc,
                        float* __restrict__ out3, float* __restrict__ out2) {
    size_t i = (size_t)blockIdx.x * 256 + threadIdx.x;
    int k = (int)(i >> 8);
    float cl = (bins[k] + 1e-5f) / (32768.0f + 8192.0f * 1e-5f) * 32768.0f;
    out3[i] = out3[i] / cl;
    if (blockIdx.x == 0 && threadIdx.x == 0)
        out2[0] = 0.25f * (float)(lossacc[0] / 8388608.0);
}

extern "C" void kernel_launch(void* const* d_in, const int* in_sizes, int n_in,
                              void* d_out, int out_size, void* d_ws, size_t ws_size,
                              hipStream_t stream) {
    const float* Z = (const float*)d_in[0];   // [32768, 256]
    const float* E = (const float*)d_in[1];   // [8192, 256]
    float* out  = (float*)d_out;
    float* out0 = out;                         // z_q_st  (8388608)
    float* out1 = out + 8388608;               // idx as float (32768)
    float* out2 = out1 + 32768;                // loss (1)
    float* out3 = out2 + 1;                    // new_embeddings (2097152)

    char* ws = (char*)d_ws;
    ushort16* Zcat  = (ushort16*)(ws + OFF_ZCAT);
    ushort16* Ecat  = (ushort16*)(ws + OFF_ECAT);
    float*  ET      = (float*)(ws + OFF_ET);
    float*  znorm   = (float*)(ws + OFF_ZN);
    float*  enorm   = (float*)(ws + OFF_EN);
    float*  pv      = (float*)(ws + OFF_PV);
    int*    pi      = (int*)  (ws + OFF_PI);
    float*  pv2     = (float*)(ws + OFF_PV2);
    int*    idxint  = (int*)  (ws + OFF_IDX);
    float*  bins    = (float*)(ws + OFF_BINS);
    int*    flagcnt = (int*)  (ws + OFF_FLAGCNT);
    double* lossacc = (double*)(ws + OFF_LOSS);
    int*    flagged = (int*)  (ws + OFF_FLAGGED);

    hipMemsetAsync(bins,    0, (size_t)NE * 4, stream);
    hipMemsetAsync(flagcnt, 0, 4, stream);
    hipMemsetAsync(lossacc, 0, 8, stream);
    hipMemsetAsync(out3,    0, (size_t)NE * EDIM * 4, stream);

    k_convert_z<<<8192, 256, 0, stream>>>(Z, Zcat);
    k_convert_e<<<2048, 256, 0, stream>>>(E, Ecat, ET);
    k_znorm  <<<N_ROWS / 256, 256, 0, stream>>>(Z, znorm);
    k_enorm  <<<NE / 256,     256, 0, stream>>>(E, enorm);
    k_gemm   <<<256 * NTILES, 256, 0, stream>>>(Zcat, Ecat, znorm, enorm, pv, pi, pv2);
    k_merge  <<<N_ROWS / 256, 256, 0, stream>>>(pv, pi, pv2, out1, idxint, flagcnt, flagged);
    k_phaseB <<<256,          256, 0, stream>>>(Z, ET, znorm, enorm, flagcnt, flagged, out1, idxint);
    k_gather <<<8388608/1024, 256, 0, stream>>>(Z, E, idxint, out0, lossacc);
    k_scatter<<<N_ROWS / 4,   256, 0, stream>>>(Z, idxint, out3, bins);
    k_final  <<<(NE*EDIM)/256,256, 0, stream>>>(bins, lossacc, out3, out2);
}

// Round 5
// 801.203 us; speedup vs baseline: 4.5295x; 1.7861x over previous
//
#include <hip/hip_runtime.h>
#include <math.h>
#include <float.h>

#define N_ROWS 32768
#define EDIM 256
#define NE 8192
#define NTILES 64            // 8192 / 128 n-tiles -> partials per row
#define DELTA 4e-3f          // rescue margin: ~7.4 sigma of dropped z.lo_e term
#define RB 8                 // rows per phase-B block

typedef unsigned int uint32;
typedef unsigned long long uint64;
typedef __attribute__((ext_vector_type(8))) short bf16x8;   // 8 bf16 = 4 VGPRs
typedef __attribute__((ext_vector_type(4))) float f32x4;

// ---- workspace layout (bytes) ----
#define OFF_ZCAT    ((size_t)0)           // 32768 x 512 bf16 [hi|lo], quarter-swizzled = 33554432
#define OFF_ECAT    ((size_t)33554432)    //  8192 x 256 bf16 hi-only, quarter-swizzled = 4194304
#define OFF_ET      ((size_t)37748736)    //  256 x 8192 f32 (E^T) = 8388608
#define OFF_ZN      ((size_t)46137344)    // 32768 f
#define OFF_EN      ((size_t)46268416)    //  8192 f
#define OFF_PV      ((size_t)46301184)    // 64 x 32768 f
#define OFF_PI      ((size_t)54689792)    // 64 x 32768 i
#define OFF_PV2     ((size_t)63078400)    // 64 x 32768 f
#define OFF_IDX     ((size_t)71467008)    // 32768 i
#define OFF_BINS    ((size_t)71598080)    //  8192 f
#define OFF_PACKED  ((size_t)71630848)    // 32768 u64 = 262144
#define OFF_FLAGCNT ((size_t)71892992)    // int (padded)
#define OFF_LOSS    ((size_t)71893248)    // double (padded)
#define OFF_FLAGGED ((size_t)71893504)    // 32768 i

__device__ __forceinline__ unsigned short f32_to_bf16_rne(float f) {
    uint32 u = __float_as_uint(f);
    uint32 r = u + 0x7fffu + ((u >> 16) & 1u);
    return (unsigned short)(r >> 16);
}

__device__ __forceinline__ void gload_lds16(const void* g, void* l) {
    __builtin_amdgcn_global_load_lds(
        (const __attribute__((address_space(1))) uint32*)g,
        (__attribute__((address_space(3))) uint32*)l, 16, 0, 0);
}

// numpy pairwise-sum emulation of sum(a*a) for n=256 (validated round 3)
__device__ __forceinline__ float np_pairwise_sumsq(const float* __restrict__ a) {
#pragma clang fp contract(off)
    float h0, h1;
    #pragma unroll 1
    for (int hb = 0; hb < 2; ++hb) {
        const float* p = a + hb * 128;
        float r0=p[0]*p[0], r1=p[1]*p[1], r2=p[2]*p[2], r3=p[3]*p[3],
              r4=p[4]*p[4], r5=p[5]*p[5], r6=p[6]*p[6], r7=p[7]*p[7];
        #pragma unroll 1
        for (int i = 8; i < 128; i += 8) {
            r0 += p[i+0]*p[i+0]; r1 += p[i+1]*p[i+1];
            r2 += p[i+2]*p[i+2]; r3 += p[i+3]*p[i+3];
            r4 += p[i+4]*p[i+4]; r5 += p[i+5]*p[i+5];
            r6 += p[i+6]*p[i+6]; r7 += p[i+7]*p[i+7];
        }
        float s = ((r0+r1)+(r2+r3))+((r4+r5)+(r6+r7));
        if (hb == 0) h0 = s; else h1 = s;
    }
    return h0 + h1;
}

__global__ void k_znorm(const float* __restrict__ Z, float* __restrict__ zn) {
    int n = blockIdx.x * 64 + threadIdx.x;
    zn[n] = np_pairwise_sumsq(Z + (size_t)n * EDIM);
}
__global__ void k_enorm(const float* __restrict__ E, float* __restrict__ en) {
    int k = blockIdx.x * 64 + threadIdx.x;
    en[k] = np_pairwise_sumsq(E + (size_t)k * EDIM);
}

// Zcat: per row 16 chunks (0-7 hi, 8-15 lo) x 4 quarters of 8 bf16.
// Global slot (r,c,q) holds logical quarter q ^ s(r), s(r)=(r>>1)&3  --
// so linear global_load_lds staging lands a swizzled (conflict-free) LDS image.
__global__ void k_convert_z(const float* __restrict__ Z, unsigned short* __restrict__ Zcat) {
    int t = threadIdx.x;
    int r = blockIdx.x * 4 + (t >> 6);   // one row per wave
    int u = t & 63;                      // 64 quarters per row
    int c = u >> 2, q = u & 3;
    int lq = q ^ ((r >> 1) & 3);
    int isLo = c >> 3;
    int k0 = (c & 7) * 32 + lq * 8;
    const float4* zp = (const float4*)(Z + (size_t)r * EDIM + k0);
    float4 a = zp[0], b = zp[1];
    float f[8] = {a.x,a.y,a.z,a.w,b.x,b.y,b.z,b.w};
    uint32 o[4];
    #pragma unroll
    for (int j = 0; j < 4; ++j) {
        unsigned short w0, w1;
        unsigned short h0 = f32_to_bf16_rne(f[2*j]);
        unsigned short h1 = f32_to_bf16_rne(f[2*j+1]);
        if (isLo) {
            w0 = f32_to_bf16_rne(f[2*j]   - __uint_as_float((uint32)h0 << 16));
            w1 = f32_to_bf16_rne(f[2*j+1] - __uint_as_float((uint32)h1 << 16));
        } else { w0 = h0; w1 = h1; }
        o[j] = (uint32)w0 | ((uint32)w1 << 16);
    }
    *(uint4*)(Zcat + (size_t)r * 512 + c * 32 + q * 8) = make_uint4(o[0],o[1],o[2],o[3]);
}

// Ecat: hi-only, 8 chunks x 4 quarters, same swizzle. Also builds f32 E^T.
__global__ void k_convert_e(const float* __restrict__ E, unsigned short* __restrict__ Ecat,
                            float* __restrict__ ET) {
    int t = threadIdx.x;
    int r = blockIdx.x * 8 + (t >> 5);   // row per half-wave
    int u = t & 31;
    int c = u >> 2, q = u & 3;
    int lq = q ^ ((r >> 1) & 3);
    int k0 = c * 32 + lq * 8;
    const float4* ep = (const float4*)(E + (size_t)r * EDIM + k0);
    float4 a = ep[0], b = ep[1];
    float f[8] = {a.x,a.y,a.z,a.w,b.x,b.y,b.z,b.w};
    uint32 o[4];
    #pragma unroll
    for (int j = 0; j < 4; ++j) {
        uint32 w0 = f32_to_bf16_rne(f[2*j]);
        uint32 w1 = f32_to_bf16_rne(f[2*j+1]);
        o[j] = w0 | (w1 << 16);
    }
    *(uint4*)(Ecat + (size_t)r * 256 + c * 32 + q * 8) = make_uint4(o[0],o[1],o[2],o[3]);
    #pragma unroll
    for (int j = 0; j < 8; ++j) ET[(size_t)(k0 + j) * NE + r] = f[j];
}

// merge two top-2 sets across 16-lane groups (butterfly), lex tie-break on idx
__device__ __forceinline__ void top2_shfl16(float& v1, int& i1, float& v2) {
    #pragma unroll
    for (int off = 1; off < 16; off <<= 1) {
        float ov1 = __shfl_xor(v1, off, 64);
        int   oi1 = __shfl_xor(i1, off, 64);
        float ov2 = __shfl_xor(v2, off, 64);
        bool take = (ov1 < v1) || (ov1 == v1 && oi1 < i1);
        float w1 = take ? ov1 : v1;
        int   wi = take ? oi1 : i1;
        float l1 = take ? v1  : ov1;
        v2 = fminf(fminf(v2, ov2), l1);
        v1 = w1; i1 = wi;
    }
}

// Phase A: (hi_z+lo_z).hi_e MFMA GEMM, virtual K=512 (A=[hi|lo], B=[hi|hi]),
// fused per-row top-2 argmin epilogue. LDS fragment reads quarter-swizzled.
__global__ __launch_bounds__(256, 4) void k_gemm(
    const unsigned short* __restrict__ Zcat, const unsigned short* __restrict__ Ecat,
    const float* __restrict__ znorm, const float* __restrict__ enorm,
    float* __restrict__ pv, int* __restrict__ pi, float* __restrict__ pv2)
{
    __shared__ unsigned short As[128*32];   // [row][32k] 64-B rows, 8 KB
    __shared__ unsigned short Bs[128*32];
    __shared__ float zns[128], ens[128];
    __shared__ float cv1[2][128]; __shared__ int ci1[2][128]; __shared__ float cv2[2][128];

    int t = threadIdx.x;
    int nt = blockIdx.x & 63, mt = blockIdx.x >> 6;   // n fastest: A-band L2 reuse
    int wid = t >> 6, lane = t & 63;
    int wm = (wid >> 1) * 64, wn = (wid & 1) * 64;

    if (t < 128) { zns[t] = znorm[mt*128 + t]; ens[t] = enorm[nt*128 + t]; }

    // staging: wave wid fills LDS j-blocks {2w,2w+1}; lane -> row j*16+(lane>>2),
    // quarter lane&3 (matches global slot layout -> swizzled LDS image)
    int j0 = wid*2, j1 = j0 + 1;
    int r0 = j0*16 + (lane >> 2), r1 = j1*16 + (lane >> 2);
    int c8 = (lane & 3) * 8;
    const unsigned short* gA0 = Zcat + (size_t)(mt*128 + r0)*512 + c8;
    const unsigned short* gA1 = Zcat + (size_t)(mt*128 + r1)*512 + c8;
    const unsigned short* gB0 = Ecat + (size_t)(nt*128 + r0)*256 + c8;
    const unsigned short* gB1 = Ecat + (size_t)(nt*128 + r1)*256 + c8;
    unsigned short* lA0 = As + j0*512;  unsigned short* lA1 = As + j1*512;
    unsigned short* lB0 = Bs + j0*512;  unsigned short* lB1 = Bs + j1*512;

    f32x4 acc[4][4];
    #pragma unroll
    for (int i = 0; i < 4; ++i)
        #pragma unroll
        for (int j = 0; j < 4; ++j) acc[i][j] = (f32x4){0.f,0.f,0.f,0.f};

    // fragment read: row = frow(+16i), quarter q=lane>>4 -> LDS quarter q^s(frow)
    int frow = lane & 15, q = lane >> 4;
    int sw = (frow >> 1) & 3;
    const unsigned short* aBase = As + (wm + frow)*32 + ((q ^ sw) * 8);
    const unsigned short* bBase = Bs + (wn + frow)*32 + ((q ^ sw) * 8);

    #pragma unroll 1
    for (int c = 0; c < 16; ++c) {
        int aOff = c * 32;           // chunks 0-7 hi, 8-15 lo
        int bOff = (c & 7) * 32;     // B = [hi|hi]
        gload_lds16(gA0 + aOff, lA0);
        gload_lds16(gA1 + aOff, lA1);
        gload_lds16(gB0 + bOff, lB0);
        gload_lds16(gB1 + bOff, lB1);
        __syncthreads();
        bf16x8 af[4], bfr[4];
        #pragma unroll
        for (int i = 0; i < 4; ++i) {
            af[i]  = *(const bf16x8*)(aBase + i*16*32);
            bfr[i] = *(const bf16x8*)(bBase + i*16*32);
        }
        #pragma unroll
        for (int i = 0; i < 4; ++i)
            #pragma unroll
            for (int j = 0; j < 4; ++j)
                acc[i][j] = __builtin_amdgcn_mfma_f32_16x16x32_bf16(af[i], bfr[j], acc[i][j], 0, 0, 0);
        __syncthreads();
    }

    // epilogue: D layout n = lane&15, m = (lane>>4)*4 + reg
    #pragma unroll
    for (int i = 0; i < 4; ++i) {
        #pragma unroll
        for (int r = 0; r < 4; ++r) {
            int mloc = wm + i*16 + q*4 + r;
            float zn = zns[mloc];
            float s[4]; int nn[4];
            #pragma unroll
            for (int j = 0; j < 4; ++j) {
                int nl = wn + j*16 + frow;
                nn[j] = nt*128 + nl;
                s[j] = (zn + ens[nl]) - 2.0f * acc[i][j][r];
            }
            float v1 = s[0], v2 = FLT_MAX; int i1 = nn[0];
            #pragma unroll
            for (int j = 1; j < 4; ++j) {
                if (s[j] < v1) { v2 = v1; v1 = s[j]; i1 = nn[j]; }
                else v2 = fminf(v2, s[j]);
            }
            top2_shfl16(v1, i1, v2);
            if (frow == 0) { cv1[wid&1][mloc] = v1; ci1[wid&1][mloc] = i1; cv2[wid&1][mloc] = v2; }
        }
    }
    __syncthreads();
    if (t < 128) {
        float v1 = cv1[0][t], v2 = cv2[0][t]; int i1 = ci1[0][t];
        float o1 = cv1[1][t], o2 = cv2[1][t]; int oi = ci1[1][t];
        if (o1 < v1 || (o1 == v1 && oi < i1)) { v2 = fminf(v1, o2); v1 = o1; i1 = oi; }
        else v2 = fminf(v2, o1);
        size_t o = (size_t)nt * N_ROWS + mt*128 + t;
        pv[o] = v1; pi[o] = i1; pv2[o] = v2;
    }
}

// merge 64 n-tile partials per row; flag rows with gap < DELTA for np-exact rescan
__global__ void k_merge(const float* __restrict__ pv, const int* __restrict__ pi,
                        const float* __restrict__ pv2,
                        float* __restrict__ out_idx_f, int* __restrict__ idxint,
                        int* __restrict__ flagcnt, int* __restrict__ flagged) {
    int g = blockIdx.x * 256 + threadIdx.x;
    float B1 = FLT_MAX, B2 = FLT_MAX; int I1 = 0;
    #pragma unroll 1
    for (int p = 0; p < NTILES; ++p) {   // ascending p == ascending k
        size_t o = (size_t)p * N_ROWS + g;
        float v1 = pv[o], v2 = pv2[o]; int i1 = pi[o];
        if (v1 < B1) { B2 = fminf(B1, v2); B1 = v1; I1 = i1; }
        else B2 = fminf(B2, v1);
    }
    out_idx_f[g] = (float)I1;
    idxint[g] = I1;
    if (B2 - B1 < DELTA) {
        int slot = atomicAdd(flagcnt, 1);
        flagged[slot] = g;
    }
}

__device__ __forceinline__ uint32 float_key(float v) {
    uint32 b = __float_as_uint(v);
    return (b & 0x80000000u) ? ~b : (b | 0x80000000u);   // monotone total order
}

// Phase B: np-exact fp32 rescan (validated round-3 semantics). Task =
// (k-slice of 1024, group of RB flagged rows); result via atomicMin on
// order-packed (score,idx) -- equal score resolves to lower idx (np argmin).
__global__ void k_phaseB(const float* __restrict__ Z, const float* __restrict__ ET,
                         const float* __restrict__ znorm, const float* __restrict__ enorm,
                         const int* __restrict__ flagcnt, const int* __restrict__ flagged,
                         uint64* __restrict__ packed) {
    __shared__ float zl[RB][256];
    __shared__ int rows[RB];
    __shared__ float sv[256]; __shared__ int si[256];
    int t = threadIdx.x;
    int cnt = *flagcnt; if (cnt > N_ROWS) cnt = N_ROWS;
    int ngrp = (cnt + RB - 1) / RB;
    int ntask = ngrp * 8;
    #pragma unroll 1
    for (int task = blockIdx.x; task < ntask; task += gridDim.x) {
        int slice = task & 7;
        int g0 = (task >> 3) * RB;
        __syncthreads();
        if (t < RB) {
            int f = g0 + t;
            rows[t] = flagged[f < cnt ? f : g0];   // clamp dup: recompute harmless
        }
        __syncthreads();
        #pragma unroll
        for (int rr = 0; rr < RB; ++rr) zl[rr][t] = Z[(size_t)rows[rr]*EDIM + t];
        __syncthreads();

        float acc[RB][4];
        #pragma unroll
        for (int rr = 0; rr < RB; ++rr)
            #pragma unroll
            for (int c = 0; c < 4; ++c) acc[rr][c] = 0.f;
        const float* eb = ET + slice*1024 + t;
        #pragma unroll 1
        for (int d = 0; d < 256; ++d) {           // sequential ascending d (np order)
            const float* ep = eb + (size_t)d * NE;
            float v0 = ep[0], v1 = ep[256], v2 = ep[512], v3 = ep[768];
            #pragma unroll
            for (int rr = 0; rr < RB; ++rr) {
                float zd = zl[rr][d];
                acc[rr][0] = fmaf(zd, v0, acc[rr][0]);
                acc[rr][1] = fmaf(zd, v1, acc[rr][1]);
                acc[rr][2] = fmaf(zd, v2, acc[rr][2]);
                acc[rr][3] = fmaf(zd, v3, acc[rr][3]);
            }
        }
        #pragma unroll 1
        for (int rr = 0; rr < RB; ++rr) {
            int row = rows[rr];
            float zn = znorm[row];
            float bv = FLT_MAX; int bi = 0x7fffffff;
            {
#pragma clang fp contract(off)
                #pragma unroll
                for (int c = 0; c < 4; ++c) {
                    int k = slice*1024 + c*256 + t;
                    float S  = zn + enorm[k];
                    float tw = 2.0f * acc[rr][c];
                    float sc = S - tw;
                    if (sc < bv || (sc == bv && k < bi)) { bv = sc; bi = k; }
                }
            }
            sv[t] = bv; si[t] = bi;
            __syncthreads();
            for (int st = 128; st > 0; st >>= 1) {
                if (t < st) {
                    float ov = sv[t+st]; int oi = si[t+st];
                    if (ov < sv[t] || (ov == sv[t] && oi < si[t])) { sv[t] = ov; si[t] = oi; }
                }
                __syncthreads();
            }
            if (t == 0) {
                uint64 pk = ((uint64)float_key(sv[0]) << 32) | (uint32)si[0];
                atomicMin(packed + row, pk);
            }
            __syncthreads();
        }
    }
}

// write back corrected idx for flagged rows
__global__ void k_fix(const int* __restrict__ flagcnt, const int* __restrict__ flagged,
                      const uint64* __restrict__ packed,
                      float* __restrict__ out_idx_f, int* __restrict__ idxint) {
    int cnt = *flagcnt; if (cnt > N_ROWS) cnt = N_ROWS;
    for (int f = blockIdx.x*256 + threadIdx.x; f < cnt; f += gridDim.x*256) {
        int row = flagged[f];
        int idx = (int)(uint32)(packed[row] & 0xffffffffu);
        out_idx_f[row] = (float)idx;
        idxint[row] = idx;
    }
}

// fused tail: z_q_st, loss, bins += 1, dw += z  (one wave per row)
__global__ void k_tail(const float* __restrict__ Z, const float* __restrict__ E,
                       const int* __restrict__ idxint,
                       float* __restrict__ out0, float* __restrict__ dw,
                       float* __restrict__ bins, double* __restrict__ lossacc) {
    __shared__ float wsum[4];
    int t = threadIdx.x;
    int w = t >> 6, lane = t & 63;
    int row = blockIdx.x * 4 + w;
    int idx = idxint[row];
    float4 z4 = ((const float4*)Z)[(size_t)row * 64 + lane];
    float4 e4 = ((const float4*)E)[(size_t)idx * 64 + lane];
    float4 d4; d4.x = e4.x - z4.x; d4.y = e4.y - z4.y; d4.z = e4.z - z4.z; d4.w = e4.w - z4.w;
    float4 o;  o.x = z4.x + d4.x;  o.y = z4.y + d4.y;  o.z = z4.z + d4.z;  o.w = z4.w + d4.w;
    ((float4*)out0)[(size_t)row * 64 + lane] = o;
    float q2 = d4.x*d4.x + d4.y*d4.y + d4.z*d4.z + d4.w*d4.w;
    #pragma unroll
    for (int off = 32; off > 0; off >>= 1) q2 += __shfl_down(q2, off, 64);
    if (lane == 0) wsum[w] = q2;
    float* dp = dw + (size_t)idx * 256 + lane * 4;
    atomicAdd(dp + 0, z4.x);
    atomicAdd(dp + 1, z4.y);
    atomicAdd(dp + 2, z4.z);
    atomicAdd(dp + 3, z4.w);
    if (lane == 0) atomicAdd(&bins[idx], 1.0f);
    __syncthreads();
    if (t == 0) atomicAdd(lossacc, (double)(wsum[0] + wsum[1] + wsum[2] + wsum[3]));
}

// new_emb = dw / cluster (in-place on out3), + loss
__global__ void k_final(const float* __restrict__ bins, const double* __restrict__ lossacc,
                        float* __restrict__ out3, float* __restrict__ out2) {
    size_t i = (size_t)blockIdx.x * 256 + threadIdx.x;
    int k = (int)(i >> 8);
    float cl = (bins[k] + 1e-5f) / (32768.0f + 8192.0f * 1e-5f) * 32768.0f;
    out3[i] = out3[i] / cl;
    if (blockIdx.x == 0 && threadIdx.x == 0)
        out2[0] = 0.25f * (float)(lossacc[0] / 8388608.0);
}

extern "C" void kernel_launch(void* const* d_in, const int* in_sizes, int n_in,
                              void* d_out, int out_size, void* d_ws, size_t ws_size,
                              hipStream_t stream) {
    const float* Z = (const float*)d_in[0];   // [32768, 256]
    const float* E = (const float*)d_in[1];   // [8192, 256]
    float* out  = (float*)d_out;
    float* out0 = out;                         // z_q_st  (8388608)
    float* out1 = out + 8388608;               // idx as float (32768)
    float* out2 = out1 + 32768;                // loss (1)
    float* out3 = out2 + 1;                    // new_embeddings (2097152)

    char* ws = (char*)d_ws;
    unsigned short* Zcat = (unsigned short*)(ws + OFF_ZCAT);
    unsigned short* Ecat = (unsigned short*)(ws + OFF_ECAT);
    float*  ET      = (float*)(ws + OFF_ET);
    float*  znorm   = (float*)(ws + OFF_ZN);
    float*  enorm   = (float*)(ws + OFF_EN);
    float*  pv      = (float*)(ws + OFF_PV);
    int*    pi      = (int*)  (ws + OFF_PI);
    float*  pv2     = (float*)(ws + OFF_PV2);
    int*    idxint  = (int*)  (ws + OFF_IDX);
    float*  bins    = (float*)(ws + OFF_BINS);
    uint64* packed  = (uint64*)(ws + OFF_PACKED);
    int*    flagcnt = (int*)  (ws + OFF_FLAGCNT);
    double* lossacc = (double*)(ws + OFF_LOSS);
    int*    flagged = (int*)  (ws + OFF_FLAGGED);

    hipMemsetAsync(bins,    0,    (size_t)NE * 4, stream);
    hipMemsetAsync(flagcnt, 0,    4, stream);
    hipMemsetAsync(lossacc, 0,    8, stream);
    hipMemsetAsync(packed,  0xFF, (size_t)N_ROWS * 8, stream);
    hipMemsetAsync(out3,    0,    (size_t)NE * EDIM * 4, stream);

    k_convert_z<<<8192, 256, 0, stream>>>(Z, Zcat);
    k_convert_e<<<1024, 256, 0, stream>>>(E, Ecat, ET);
    k_znorm  <<<N_ROWS / 64,  64, 0, stream>>>(Z, znorm);
    k_enorm  <<<NE / 64,      64, 0, stream>>>(E, enorm);
    k_gemm   <<<256 * NTILES, 256, 0, stream>>>(Zcat, Ecat, znorm, enorm, pv, pi, pv2);
    k_merge  <<<N_ROWS / 256, 256, 0, stream>>>(pv, pi, pv2, out1, idxint, flagcnt, flagged);
    k_phaseB <<<2048,         256, 0, stream>>>(Z, ET, znorm, enorm, flagcnt, flagged, packed);
    k_fix    <<<32,           256, 0, stream>>>(flagcnt, flagged, packed, out1, idxint);
    k_tail   <<<N_ROWS / 4,   256, 0, stream>>>(Z, E, idxint, out0, out3, bins, lossacc);
    k_final  <<<(NE*EDIM)/256,256, 0, stream>>>(bins, lossacc, out3, out2);
}

// Round 6
// 736.390 us; speedup vs baseline: 4.9281x; 1.0880x over previous
//
#include <hip/hip_runtime.h>
#include <math.h>
#include <float.h>

#define N_ROWS 32768
#define EDIM 256
#define NE 8192
#define NTILES 64            // 8192 / 128 n-tiles -> partials per row
#define DELTA 4e-3f          // rescue margin: ~7.4 sigma of dropped z.lo_e term
#define RB 8                 // rows per phase-B block

typedef unsigned int uint32;
typedef unsigned long long uint64;
typedef __attribute__((ext_vector_type(8))) short bf16x8;   // 8 bf16 = 4 VGPRs
typedef __attribute__((ext_vector_type(4))) float f32x4;

// ---- workspace layout (bytes) ----
#define OFF_ZCAT    ((size_t)0)           // 32768 x 512 bf16 [hi|lo], quarter-swizzled = 33554432
#define OFF_ECAT    ((size_t)33554432)    //  8192 x 256 bf16 hi-only, quarter-swizzled = 4194304
#define OFF_ET      ((size_t)37748736)    //  256 x 8192 f32 (E^T) = 8388608
#define OFF_EN      ((size_t)46268416)    //  8192 f
#define OFF_PV      ((size_t)46301184)    // 64 x 32768 f
#define OFF_PI      ((size_t)54689792)    // 64 x 32768 i
#define OFF_PV2     ((size_t)63078400)    // 64 x 32768 f
#define OFF_IDX     ((size_t)71467008)    // 32768 i
#define OFF_BINS    ((size_t)71598080)    //  8192 f
#define OFF_PACKED  ((size_t)71630848)    // 32768 u64 = 262144
#define OFF_FLAGCNT ((size_t)71892992)    // int (padded)
#define OFF_LOSS    ((size_t)71893248)    // double (padded)
#define OFF_FLAGGED ((size_t)71893504)    // 32768 i

__device__ __forceinline__ unsigned short f32_to_bf16_rne(float f) {
    uint32 u = __float_as_uint(f);
    uint32 r = u + 0x7fffu + ((u >> 16) & 1u);
    return (unsigned short)(r >> 16);
}

__device__ __forceinline__ void gload_lds16(const void* g, void* l) {
    __builtin_amdgcn_global_load_lds(
        (const __attribute__((address_space(1))) uint32*)g,
        (__attribute__((address_space(3))) uint32*)l, 16, 0, 0);
}

// numpy pairwise-sum emulation of sum(a*a) for n=256 (validated round 3)
__device__ __forceinline__ float np_pairwise_sumsq(const float* a) {
#pragma clang fp contract(off)
    float h0, h1;
    #pragma unroll 1
    for (int hb = 0; hb < 2; ++hb) {
        const float* p = a + hb * 128;
        float r0=p[0]*p[0], r1=p[1]*p[1], r2=p[2]*p[2], r3=p[3]*p[3],
              r4=p[4]*p[4], r5=p[5]*p[5], r6=p[6]*p[6], r7=p[7]*p[7];
        #pragma unroll 1
        for (int i = 8; i < 128; i += 8) {
            r0 += p[i+0]*p[i+0]; r1 += p[i+1]*p[i+1];
            r2 += p[i+2]*p[i+2]; r3 += p[i+3]*p[i+3];
            r4 += p[i+4]*p[i+4]; r5 += p[i+5]*p[i+5];
            r6 += p[i+6]*p[i+6]; r7 += p[i+7]*p[i+7];
        }
        float s = ((r0+r1)+(r2+r3))+((r4+r5)+(r6+r7));
        if (hb == 0) h0 = s; else h1 = s;
    }
    return h0 + h1;
}

__global__ void k_enorm(const float* __restrict__ E, float* __restrict__ en) {
    int k = blockIdx.x * 64 + threadIdx.x;
    en[k] = np_pairwise_sumsq(E + (size_t)k * EDIM);
}

// Zcat: per row 16 chunks (0-7 hi, 8-15 lo) x 4 quarters of 8 bf16.
// Global slot (r,c,q) holds logical quarter q ^ s(r), s(r)=(r>>1)&3  --
// so linear global_load_lds staging lands a swizzled (conflict-free) LDS image.
__global__ void k_convert_z(const float* __restrict__ Z, unsigned short* __restrict__ Zcat) {
    int t = threadIdx.x;
    int r = blockIdx.x * 4 + (t >> 6);   // one row per wave
    int u = t & 63;                      // 64 quarters per row
    int c = u >> 2, q = u & 3;
    int lq = q ^ ((r >> 1) & 3);
    int isLo = c >> 3;
    int k0 = (c & 7) * 32 + lq * 8;
    const float4* zp = (const float4*)(Z + (size_t)r * EDIM + k0);
    float4 a = zp[0], b = zp[1];
    float f[8] = {a.x,a.y,a.z,a.w,b.x,b.y,b.z,b.w};
    uint32 o[4];
    #pragma unroll
    for (int j = 0; j < 4; ++j) {
        unsigned short w0, w1;
        unsigned short h0 = f32_to_bf16_rne(f[2*j]);
        unsigned short h1 = f32_to_bf16_rne(f[2*j+1]);
        if (isLo) {
            w0 = f32_to_bf16_rne(f[2*j]   - __uint_as_float((uint32)h0 << 16));
            w1 = f32_to_bf16_rne(f[2*j+1] - __uint_as_float((uint32)h1 << 16));
        } else { w0 = h0; w1 = h1; }
        o[j] = (uint32)w0 | ((uint32)w1 << 16);
    }
    *(uint4*)(Zcat + (size_t)r * 512 + c * 32 + q * 8) = make_uint4(o[0],o[1],o[2],o[3]);
}

// Ecat: hi-only, 8 chunks x 4 quarters, same swizzle. Also builds f32 E^T.
__global__ void k_convert_e(const float* __restrict__ E, unsigned short* __restrict__ Ecat,
                            float* __restrict__ ET) {
    int t = threadIdx.x;
    int r = blockIdx.x * 8 + (t >> 5);   // row per half-wave
    int u = t & 31;
    int c = u >> 2, q = u & 3;
    int lq = q ^ ((r >> 1) & 3);
    int k0 = c * 32 + lq * 8;
    const float4* ep = (const float4*)(E + (size_t)r * EDIM + k0);
    float4 a = ep[0], b = ep[1];
    float f[8] = {a.x,a.y,a.z,a.w,b.x,b.y,b.z,b.w};
    uint32 o[4];
    #pragma unroll
    for (int j = 0; j < 4; ++j) {
        uint32 w0 = f32_to_bf16_rne(f[2*j]);
        uint32 w1 = f32_to_bf16_rne(f[2*j+1]);
        o[j] = w0 | (w1 << 16);
    }
    *(uint4*)(Ecat + (size_t)r * 256 + c * 32 + q * 8) = make_uint4(o[0],o[1],o[2],o[3]);
    #pragma unroll
    for (int j = 0; j < 8; ++j) ET[(size_t)(k0 + j) * NE + r] = f[j];
}

// merge two top-2 sets across 16-lane groups (butterfly), lex tie-break on idx
__device__ __forceinline__ void top2_shfl16(float& v1, int& i1, float& v2) {
    #pragma unroll
    for (int off = 1; off < 16; off <<= 1) {
        float ov1 = __shfl_xor(v1, off, 64);
        int   oi1 = __shfl_xor(i1, off, 64);
        float ov2 = __shfl_xor(v2, off, 64);
        bool take = (ov1 < v1) || (ov1 == v1 && oi1 < i1);
        float w1 = take ? ov1 : v1;
        int   wi = take ? oi1 : i1;
        float l1 = take ? v1  : ov1;
        v2 = fminf(fminf(v2, ov2), l1);
        v1 = w1; i1 = wi;
    }
}

// Phase A: (hi_z+lo_z).hi_e MFMA GEMM, virtual K=512. B staged ONCE per
// 32-k chunk and reused by the A-hi and A-lo MFMA sets (32 MFMA / barrier).
// Score = en - 2*dot (per-row zn shift dropped: argmin/gap invariant).
__global__ __launch_bounds__(256, 4) void k_gemm(
    const unsigned short* __restrict__ Zcat, const unsigned short* __restrict__ Ecat,
    const float* __restrict__ enorm,
    float* __restrict__ pv, int* __restrict__ pi, float* __restrict__ pv2)
{
    __shared__ unsigned short Ah[128*32];   // A hi chunk, 8 KB
    __shared__ unsigned short Al[128*32];   // A lo chunk, 8 KB
    __shared__ unsigned short Bs[128*32];   // B hi chunk, 8 KB
    __shared__ float ens[128];
    __shared__ float cv1[2][128]; __shared__ int ci1[2][128]; __shared__ float cv2[2][128];

    int t = threadIdx.x;
    int nt = blockIdx.x & 63, mt = blockIdx.x >> 6;   // n fastest: A-band L2 reuse
    int wid = t >> 6, lane = t & 63;
    int wm = (wid >> 1) * 64, wn = (wid & 1) * 64;

    if (t < 128) ens[t] = enorm[nt*128 + t];

    // staging: wave wid fills LDS j-blocks {2w,2w+1}; lane -> row j*16+(lane>>2),
    // quarter lane&3 (matches global slot layout -> swizzled LDS image)
    int j0 = wid*2, j1 = j0 + 1;
    int r0 = j0*16 + (lane >> 2), r1 = j1*16 + (lane >> 2);
    int c8 = (lane & 3) * 8;
    const unsigned short* gA0 = Zcat + (size_t)(mt*128 + r0)*512 + c8;
    const unsigned short* gA1 = Zcat + (size_t)(mt*128 + r1)*512 + c8;
    const unsigned short* gB0 = Ecat + (size_t)(nt*128 + r0)*256 + c8;
    const unsigned short* gB1 = Ecat + (size_t)(nt*128 + r1)*256 + c8;
    unsigned short* lAh0 = Ah + j0*512;  unsigned short* lAh1 = Ah + j1*512;
    unsigned short* lAl0 = Al + j0*512;  unsigned short* lAl1 = Al + j1*512;
    unsigned short* lB0  = Bs + j0*512;  unsigned short* lB1  = Bs + j1*512;

    f32x4 acc[4][4];
    #pragma unroll
    for (int i = 0; i < 4; ++i)
        #pragma unroll
        for (int j = 0; j < 4; ++j) acc[i][j] = (f32x4){0.f,0.f,0.f,0.f};

    // fragment read: row = frow(+16i), quarter q=lane>>4 -> LDS quarter q^s(frow)
    int frow = lane & 15, q = lane >> 4;
    int sw = (frow >> 1) & 3;
    const unsigned short* ahBase = Ah + (wm + frow)*32 + ((q ^ sw) * 8);
    const unsigned short* alBase = Al + (wm + frow)*32 + ((q ^ sw) * 8);
    const unsigned short* bBase  = Bs + (wn + frow)*32 + ((q ^ sw) * 8);

    #pragma unroll 1
    for (int c = 0; c < 8; ++c) {
        int aOff = c * 32;            // hi chunk c; lo chunk c+8 at +256
        gload_lds16(gA0 + aOff,       lAh0);
        gload_lds16(gA1 + aOff,       lAh1);
        gload_lds16(gA0 + aOff + 256, lAl0);
        gload_lds16(gA1 + aOff + 256, lAl1);
        gload_lds16(gB0 + aOff,       lB0);
        gload_lds16(gB1 + aOff,       lB1);
        __syncthreads();
        bf16x8 af[4], bfr[4];
        #pragma unroll
        for (int i = 0; i < 4; ++i) bfr[i] = *(const bf16x8*)(bBase + i*16*32);
        #pragma unroll
        for (int i = 0; i < 4; ++i) af[i] = *(const bf16x8*)(ahBase + i*16*32);
        #pragma unroll
        for (int i = 0; i < 4; ++i)
            #pragma unroll
            for (int j = 0; j < 4; ++j)
                acc[i][j] = __builtin_amdgcn_mfma_f32_16x16x32_bf16(af[i], bfr[j], acc[i][j], 0, 0, 0);
        #pragma unroll
        for (int i = 0; i < 4; ++i) af[i] = *(const bf16x8*)(alBase + i*16*32);  // reuse regs
        #pragma unroll
        for (int i = 0; i < 4; ++i)
            #pragma unroll
            for (int j = 0; j < 4; ++j)
                acc[i][j] = __builtin_amdgcn_mfma_f32_16x16x32_bf16(af[i], bfr[j], acc[i][j], 0, 0, 0);
        __syncthreads();
    }

    // epilogue: D layout n = lane&15, m = (lane>>4)*4 + reg
    #pragma unroll
    for (int i = 0; i < 4; ++i) {
        #pragma unroll
        for (int r = 0; r < 4; ++r) {
            int mloc = wm + i*16 + q*4 + r;
            float s[4]; int nn[4];
            #pragma unroll
            for (int j = 0; j < 4; ++j) {
                int nl = wn + j*16 + frow;
                nn[j] = nt*128 + nl;
                s[j] = ens[nl] - 2.0f * acc[i][j][r];
            }
            float v1 = s[0], v2 = FLT_MAX; int i1 = nn[0];
            #pragma unroll
            for (int j = 1; j < 4; ++j) {
                if (s[j] < v1) { v2 = v1; v1 = s[j]; i1 = nn[j]; }
                else v2 = fminf(v2, s[j]);
            }
            top2_shfl16(v1, i1, v2);
            if (frow == 0) { cv1[wid&1][mloc] = v1; ci1[wid&1][mloc] = i1; cv2[wid&1][mloc] = v2; }
        }
    }
    __syncthreads();
    if (t < 128) {
        float v1 = cv1[0][t], v2 = cv2[0][t]; int i1 = ci1[0][t];
        float o1 = cv1[1][t], o2 = cv2[1][t]; int oi = ci1[1][t];
        if (o1 < v1 || (o1 == v1 && oi < i1)) { v2 = fminf(v1, o2); v1 = o1; i1 = oi; }
        else v2 = fminf(v2, o1);
        size_t o = (size_t)nt * N_ROWS + mt*128 + t;
        pv[o] = v1; pi[o] = i1; pv2[o] = v2;
    }
}

// merge 64 n-tile partials per row; flag rows with gap < DELTA for np-exact rescan
__global__ void k_merge(const float* __restrict__ pv, const int* __restrict__ pi,
                        const float* __restrict__ pv2,
                        float* __restrict__ out_idx_f, int* __restrict__ idxint,
                        int* __restrict__ flagcnt, int* __restrict__ flagged) {
    int g = blockIdx.x * 256 + threadIdx.x;
    float B1 = FLT_MAX, B2 = FLT_MAX; int I1 = 0;
    #pragma unroll 1
    for (int p = 0; p < NTILES; ++p) {   // ascending p == ascending k
        size_t o = (size_t)p * N_ROWS + g;
        float v1 = pv[o], v2 = pv2[o]; int i1 = pi[o];
        if (v1 < B1) { B2 = fminf(B1, v2); B1 = v1; I1 = i1; }
        else B2 = fminf(B2, v1);
    }
    out_idx_f[g] = (float)I1;
    idxint[g] = I1;
    if (B2 - B1 < DELTA) {
        int slot = atomicAdd(flagcnt, 1);
        flagged[slot] = g;
    }
}

__device__ __forceinline__ uint32 float_key(float v) {
    uint32 b = __float_as_uint(v);
    return (b & 0x80000000u) ? ~b : (b | 0x80000000u);   // monotone total order
}

// Phase B: np-exact fp32 rescan (validated round-3 semantics). Task =
// (k-slice of 1024, group of RB flagged rows); zn computed in-kernel (np order);
// result via atomicMin on order-packed (score,idx).
__global__ void k_phaseB(const float* __restrict__ Z, const float* __restrict__ ET,
                         const float* __restrict__ enorm,
                         const int* __restrict__ flagcnt, const int* __restrict__ flagged,
                         uint64* __restrict__ packed) {
    __shared__ float zl[RB][256];
    __shared__ float znl[RB];
    __shared__ int rows[RB];
    __shared__ float sv[256]; __shared__ int si[256];
    int t = threadIdx.x;
    int cnt = *flagcnt; if (cnt > N_ROWS) cnt = N_ROWS;
    int ngrp = (cnt + RB - 1) / RB;
    int ntask = ngrp * 8;
    #pragma unroll 1
    for (int task = blockIdx.x; task < ntask; task += gridDim.x) {
        int slice = task & 7;
        int g0 = (task >> 3) * RB;
        __syncthreads();
        if (t < RB) {
            int f = g0 + t;
            rows[t] = flagged[f < cnt ? f : g0];   // clamp dup: recompute harmless
        }
        __syncthreads();
        #pragma unroll
        for (int rr = 0; rr < RB; ++rr) zl[rr][t] = Z[(size_t)rows[rr]*EDIM + t];
        __syncthreads();
        if (t < RB) znl[t] = np_pairwise_sumsq(&zl[t][0]);
        __syncthreads();

        float acc[RB][4];
        #pragma unroll
        for (int rr = 0; rr < RB; ++rr)
            #pragma unroll
            for (int c = 0; c < 4; ++c) acc[rr][c] = 0.f;
        const float* eb = ET + slice*1024 + t;
        #pragma unroll 1
        for (int d = 0; d < 256; ++d) {           // sequential ascending d (np order)
            const float* ep = eb + (size_t)d * NE;
            float v0 = ep[0], v1 = ep[256], v2 = ep[512], v3 = ep[768];
            #pragma unroll
            for (int rr = 0; rr < RB; ++rr) {
                float zd = zl[rr][d];
                acc[rr][0] = fmaf(zd, v0, acc[rr][0]);
                acc[rr][1] = fmaf(zd, v1, acc[rr][1]);
                acc[rr][2] = fmaf(zd, v2, acc[rr][2]);
                acc[rr][3] = fmaf(zd, v3, acc[rr][3]);
            }
        }
        #pragma unroll 1
        for (int rr = 0; rr < RB; ++rr) {
            int row = rows[rr];
            float zn = znl[rr];
            float bv = FLT_MAX; int bi = 0x7fffffff;
            {
#pragma clang fp contract(off)
                #pragma unroll
                for (int c = 0; c < 4; ++c) {
                    int k = slice*1024 + c*256 + t;
                    float S  = zn + enorm[k];
                    float tw = 2.0f * acc[rr][c];
                    float sc = S - tw;
                    if (sc < bv || (sc == bv && k < bi)) { bv = sc; bi = k; }
                }
            }
            sv[t] = bv; si[t] = bi;
            __syncthreads();
            for (int st = 128; st > 0; st >>= 1) {
                if (t < st) {
                    float ov = sv[t+st]; int oi = si[t+st];
                    if (ov < sv[t] || (ov == sv[t] && oi < si[t])) { sv[t] = ov; si[t] = oi; }
                }
                __syncthreads();
            }
            if (t == 0) {
                uint64 pk = ((uint64)float_key(sv[0]) << 32) | (uint32)si[0];
                atomicMin(packed + row, pk);
            }
            __syncthreads();
        }
    }
}

// write back corrected idx for flagged rows
__global__ void k_fix(const int* __restrict__ flagcnt, const int* __restrict__ flagged,
                      const uint64* __restrict__ packed,
                      float* __restrict__ out_idx_f, int* __restrict__ idxint) {
    int cnt = *flagcnt; if (cnt > N_ROWS) cnt = N_ROWS;
    for (int f = blockIdx.x*256 + threadIdx.x; f < cnt; f += gridDim.x*256) {
        int row = flagged[f];
        int idx = (int)(uint32)(packed[row] & 0xffffffffu);
        out_idx_f[row] = (float)idx;
        idxint[row] = idx;
    }
}

// fused tail: z_q_st, loss, bins += 1, dw += z  (one wave per row)
__global__ void k_tail(const float* __restrict__ Z, const float* __restrict__ E,
                       const int* __restrict__ idxint,
                       float* __restrict__ out0, float* __restrict__ dw,
                       float* __restrict__ bins, double* __restrict__ lossacc) {
    __shared__ float wsum[4];
    int t = threadIdx.x;
    int w = t >> 6, lane = t & 63;
    int row = blockIdx.x * 4 + w;
    int idx = idxint[row];
    float4 z4 = ((const float4*)Z)[(size_t)row * 64 + lane];
    float4 e4 = ((const float4*)E)[(size_t)idx * 64 + lane];
    float4 d4; d4.x = e4.x - z4.x; d4.y = e4.y - z4.y; d4.z = e4.z - z4.z; d4.w = e4.w - z4.w;
    float4 o;  o.x = z4.x + d4.x;  o.y = z4.y + d4.y;  o.z = z4.z + d4.z;  o.w = z4.w + d4.w;
    ((float4*)out0)[(size_t)row * 64 + lane] = o;
    float q2 = d4.x*d4.x + d4.y*d4.y + d4.z*d4.z + d4.w*d4.w;
    #pragma unroll
    for (int off = 32; off > 0; off >>= 1) q2 += __shfl_down(q2, off, 64);
    if (lane == 0) wsum[w] = q2;
    float* dp = dw + (size_t)idx * 256 + lane * 4;
    atomicAdd(dp + 0, z4.x);
    atomicAdd(dp + 1, z4.y);
    atomicAdd(dp + 2, z4.z);
    atomicAdd(dp + 3, z4.w);
    if (lane == 0) atomicAdd(&bins[idx], 1.0f);
    __syncthreads();
    if (t == 0) atomicAdd(lossacc, (double)(wsum[0] + wsum[1] + wsum[2] + wsum[3]));
}

// new_emb = dw / cluster (in-place on out3), + loss
__global__ void k_final(const float* __restrict__ bins, const double* __restrict__ lossacc,
                        float* __restrict__ out3, float* __restrict__ out2) {
    size_t i = (size_t)blockIdx.x * 256 + threadIdx.x;
    int k = (int)(i >> 8);
    float cl = (bins[k] + 1e-5f) / (32768.0f + 8192.0f * 1e-5f) * 32768.0f;
    out3[i] = out3[i] / cl;
    if (blockIdx.x == 0 && threadIdx.x == 0)
        out2[0] = 0.25f * (float)(lossacc[0] / 8388608.0);
}

extern "C" void kernel_launch(void* const* d_in, const int* in_sizes, int n_in,
                              void* d_out, int out_size, void* d_ws, size_t ws_size,
                              hipStream_t stream) {
    const float* Z = (const float*)d_in[0];   // [32768, 256]
    const float* E = (const float*)d_in[1];   // [8192, 256]
    float* out  = (float*)d_out;
    float* out0 = out;                         // z_q_st  (8388608)
    float* out1 = out + 8388608;               // idx as float (32768)
    float* out2 = out1 + 32768;                // loss (1)
    float* out3 = out2 + 1;                    // new_embeddings (2097152)

    char* ws = (char*)d_ws;
    unsigned short* Zcat = (unsigned short*)(ws + OFF_ZCAT);
    unsigned short* Ecat = (unsigned short*)(ws + OFF_ECAT);
    float*  ET      = (float*)(ws + OFF_ET);
    float*  enorm   = (float*)(ws + OFF_EN);
    float*  pv      = (float*)(ws + OFF_PV);
    int*    pi      = (int*)  (ws + OFF_PI);
    float*  pv2     = (float*)(ws + OFF_PV2);
    int*    idxint  = (int*)  (ws + OFF_IDX);
    float*  bins    = (float*)(ws + OFF_BINS);
    uint64* packed  = (uint64*)(ws + OFF_PACKED);
    int*    flagcnt = (int*)  (ws + OFF_FLAGCNT);
    double* lossacc = (double*)(ws + OFF_LOSS);
    int*    flagged = (int*)  (ws + OFF_FLAGGED);

    hipMemsetAsync(bins,    0,    (size_t)NE * 4, stream);
    hipMemsetAsync(flagcnt, 0,    4, stream);
    hipMemsetAsync(lossacc, 0,    8, stream);
    hipMemsetAsync(packed,  0xFF, (size_t)N_ROWS * 8, stream);
    hipMemsetAsync(out3,    0,    (size_t)NE * EDIM * 4, stream);

    k_convert_z<<<8192, 256, 0, stream>>>(Z, Zcat);
    k_convert_e<<<1024, 256, 0, stream>>>(E, Ecat, ET);
    k_enorm  <<<NE / 64,      64, 0, stream>>>(E, enorm);
    k_gemm   <<<256 * NTILES, 256, 0, stream>>>(Zcat, Ecat, enorm, pv, pi, pv2);
    k_merge  <<<N_ROWS / 256, 256, 0, stream>>>(pv, pi, pv2, out1, idxint, flagcnt, flagged);
    k_phaseB <<<2048,         256, 0, stream>>>(Z, ET, enorm, flagcnt, flagged, packed);
    k_fix    <<<32,           256, 0, stream>>>(flagcnt, flagged, packed, out1, idxint);
    k_tail   <<<N_ROWS / 4,   256, 0, stream>>>(Z, E, idxint, out0, out3, bins, lossacc);
    k_final  <<<(NE*EDIM)/256,256, 0, stream>>>(bins, lossacc, out3, out2);
}